// Round 17
// baseline (628.024 us; speedup 1.0000x reference)
//
#include <hip/hip_runtime.h>

typedef unsigned short u16;
typedef __attribute__((ext_vector_type(4))) float f4;
typedef __attribute__((ext_vector_type(4))) float f32x4;
typedef __attribute__((ext_vector_type(8))) short short8;
typedef __attribute__((ext_vector_type(4))) unsigned short u16x4;

#define DEV static __device__ __forceinline__

DEV u16 f2bf(float f) {                    // round-to-nearest-even f32->bf16
  unsigned u = __float_as_uint(f);
  u += 0x7fffu + ((u >> 16) & 1u);
  return (u16)(u >> 16);
}
DEV float siluf(float z) { return z / (1.f + __expf(-z)); }

// async global->LDS, 16B per lane (wave-uniform LDS base + lane*16)
DEV void gload16(const u16* g, const u16* l) {
  __builtin_amdgcn_global_load_lds(
      (const __attribute__((address_space(1))) unsigned int*)(unsigned long long)g,
      (__attribute__((address_space(3))) unsigned int*)(unsigned int)(unsigned long long)l,
      16, 0, 0);
}

// ---------------- batched weight converts (6 mamba weights + proj_w) ----------------
struct CvtArgs {
  const float* src[7];
  u16* dst[7];
  int bstart[8];
  int nq[7];
};

DEV void cvt_plain(const float* __restrict__ s, u16* __restrict__ d, int q, int nq) {
  if (q < nq) {
    f4 v = ((const f4*)s)[q];
    u16x4 o;
#pragma unroll
    for (int e = 0; e < 4; ++e) o[e] = f2bf(v[e]);
    ((u16x4*)d)[q] = o;
  }
}

__global__ void k_cvtmulti(CvtArgs a) {
  int b = blockIdx.x;
  int i = 0;
#pragma unroll
  for (int j = 1; j < 7; ++j) i += (b >= a.bstart[j]);
#pragma unroll
  for (int j = 0; j < 7; ++j) {
    if (i == j)
      cvt_plain(a.src[j], a.dst[j], (b - a.bstart[j]) * 256 + threadIdx.x, a.nq[j]);
  }
}

// ---------------- conv weight transpose [O][I][3] -> [I][3][O] ----------------
__global__ void k_wtrans(const float* __restrict__ in, float* __restrict__ out, int O, int I) {
  int n = O * I * 3;
  for (int g = blockIdx.x * blockDim.x + threadIdx.x; g < n; g += gridDim.x * blockDim.x) {
    int o = g / (I * 3);
    int rem = g - o * (I * 3);
    out[rem * O + o] = in[g];
  }
}

// ---------------- audio conv1: [2,80,1024] -> relu -> a1t [2,1024,192] ----------------
__global__ __launch_bounds__(192) void k_conv1(const float* __restrict__ audio,
    const float* __restrict__ w1t, const float* __restrict__ b1, float* __restrict__ a1t) {
  __shared__ float s[80][18];
  int bx = blockIdx.x;
  int b = bx >> 6, l0 = (bx & 63) << 4;
  int tid = threadIdx.x;
  for (int i = tid; i < 80 * 18; i += 192) {
    int ci = i / 18, dl = i - ci * 18;
    int l = l0 + dl - 1;
    s[ci][dl] = (l >= 0 && l < 1024) ? audio[(b * 80 + ci) * 1024 + l] : 0.f;
  }
  __syncthreads();
  int co = tid;
  float acc[16];
  float bias = b1[co];
#pragma unroll
  for (int i = 0; i < 16; ++i) acc[i] = bias;
  for (int ci = 0; ci < 80; ++ci) {
#pragma unroll
    for (int j = 0; j < 3; ++j) {
      float w = w1t[(ci * 3 + j) * 192 + co];
#pragma unroll
      for (int ls = 0; ls < 16; ++ls) acc[ls] = fmaf(s[ci][ls + j], w, acc[ls]);
    }
  }
#pragma unroll
  for (int ls = 0; ls < 16; ++ls) {
    float v = acc[ls] > 0.f ? acc[ls] : 0.f;
    a1t[(b * 1024 + l0 + ls) * 192 + co] = v;
  }
}

// ---------------- audio conv2: a1t -> bf16 X rows [b*2048 + l][384] ----------------
__global__ __launch_bounds__(384) void k_conv2b(const float* __restrict__ a1t,
    const float* __restrict__ w2t, const float* __restrict__ b2, u16* __restrict__ Xb) {
  __shared__ float s[10][192];
  int bx = blockIdx.x;
  int b = bx >> 7, l0 = (bx & 127) << 3;
  int tid = threadIdx.x;
  for (int i = tid; i < 10 * 192; i += 384) {
    int dl = i / 192, ci = i - dl * 192;
    int l = l0 + dl - 1;
    s[dl][ci] = (l >= 0 && l < 1024) ? a1t[(b * 1024 + l) * 192 + ci] : 0.f;
  }
  __syncthreads();
  int co = tid;
  float acc[8];
  float bias = b2[co];
#pragma unroll
  for (int i = 0; i < 8; ++i) acc[i] = bias;
  for (int ci = 0; ci < 192; ++ci) {
#pragma unroll
    for (int j = 0; j < 3; ++j) {
      float w = w2t[(ci * 3 + j) * 384 + co];
#pragma unroll
      for (int ls = 0; ls < 8; ++ls) acc[ls] = fmaf(s[ls + j][ci], w, acc[ls]);
    }
  }
#pragma unroll
  for (int ls = 0; ls < 8; ++ls)
    Xb[((size_t)(b * 2048 + l0 + ls)) * 384 + co] = f2bf(acc[ls]);
}

// ---------------- text embedding gather -> bf16 X rows [b*2048+1024+t] ----------------
__global__ void k_embedb(const int* __restrict__ tok, const float* __restrict__ emb,
                         u16* __restrict__ Xb) {
  int gid = blockIdx.x * blockDim.x + threadIdx.x;
  if (gid >= 2 * 1024 * 96) return;
  int q = gid % 96;
  int rt = gid / 96;
  int b = rt >> 10, t = rt & 1023;
  int tk = tok[b * 1024 + t];
  f4 v = *(const f4*)(emb + (size_t)tk * 384 + q * 4);
  u16x4 o;
#pragma unroll
  for (int e = 0; e < 4; ++e) o[e] = f2bf(v[e]);
  *(u16x4*)(Xb + ((size_t)(b * 2048 + 1024 + t)) * 384 + q * 4) = o;
}

// ---------------- fused depthwise conv(K=4)+silu + xproj GEMM ----------------
// block = 16 rows x 768 ch, 4 waves; wave w owns K-quarter [w*192,(w+1)*192).
// Lane: conv+silu for row (lane&15), 8-ch groups (k-off (lane>>4)*8) -> xi f32
// to global + bf16 A-frag in regs -> MFMA vs Wx rows (out cols). 4-way split-K
// reduced via LDS; xdbl [16][56] f32. Operand/output lane maps mirror k_gemm2.
__global__ __launch_bounds__(256) void k_dwx(
    const float* __restrict__ xz, const float* __restrict__ cw,
    const float* __restrict__ cb, const u16* __restrict__ Wx,
    float* __restrict__ xif, float* __restrict__ xdbl) {
  __shared__ float s_cw[3072], s_cb[768];
  __shared__ float part[4][16][64];
  int t = threadIdx.x, w = t >> 6, lane = t & 63;
  int fr = lane & 15, hi = lane >> 4;
  for (int i = t; i < 3072; i += 256) s_cw[i] = cw[i];
  for (int i = t; i < 768; i += 256) s_cb[i] = cb[i];
  int r0 = blockIdx.x << 4;
  int r = r0 + fr;                 // global row (16 rows stay in one batch: 2048%16==0)
  int l = r & 2047;
  __syncthreads();
  f32x4 acc[4] = {};
  for (int c = 0; c < 6; ++c) {
    int ch = w * 192 + c * 32 + hi * 8;
    float v[8];
#pragma unroll
    for (int e = 0; e < 8; ++e) v[e] = s_cb[ch + e];
#pragma unroll
    for (int j = 0; j < 4; ++j) {
      if (l - 3 + j >= 0) {
        const float* xp = xz + (size_t)(r - 3 + j) * 1536 + ch;
        f4 a0 = *(const f4*)xp, a1 = *(const f4*)(xp + 4);
#pragma unroll
        for (int e = 0; e < 4; ++e) {
          v[e]     = fmaf(a0[e], s_cw[(ch + e) * 4 + j], v[e]);
          v[4 + e] = fmaf(a1[e], s_cw[(ch + 4 + e) * 4 + j], v[4 + e]);
        }
      }
    }
    short8 af;
    f4 o0, o1;
#pragma unroll
    for (int e = 0; e < 4; ++e) {
      float s0 = siluf(v[e]), s1 = siluf(v[4 + e]);
      o0[e] = s0; o1[e] = s1;
      af[e] = (short)f2bf(s0); af[4 + e] = (short)f2bf(s1);
    }
    *(f4*)(xif + (size_t)r * 768 + ch) = o0;
    *(f4*)(xif + (size_t)r * 768 + ch + 4) = o1;
#pragma unroll
    for (int nf = 0; nf < 4; ++nf) {
      int col = nf * 16 + fr;
      int wr = (col < 56) ? col : 55;        // cols 56..63 discarded at write
      short8 wf = *(const short8*)(Wx + (size_t)wr * 768 + ch);
      acc[nf] = __builtin_amdgcn_mfma_f32_16x16x32_bf16(af, wf, acc[nf], 0, 0, 0);
    }
  }
#pragma unroll
  for (int nf = 0; nf < 4; ++nf)
#pragma unroll
    for (int rr = 0; rr < 4; ++rr)
      part[w][hi * 4 + rr][nf * 16 + fr] = acc[nf][rr];
  __syncthreads();
#pragma unroll
  for (int kk = 0; kk < 4; ++kk) {
    int idx = t * 4 + kk;
    int rr = idx >> 6, cc = idx & 63;
    if (cc < 56) {
      float s = part[0][rr][cc] + part[1][rr][cc] + part[2][rr][cc] + part[3][rr][cc];
      xdbl[(size_t)(r0 + rr) * 56 + cc] = s;
    }
  }
}

// ---------------- bf16 MFMA GEMM: 2-buffer LDS + counted-vmcnt pipeline (T4) ----------------
template <int TILE, int BIAS, int ACT, int OUTB, int SWZ>
__global__ __launch_bounds__(256) void k_gemm2(
    const u16* __restrict__ A, int lda, const u16* __restrict__ W, int ldw,
    const float* __restrict__ bias, float* __restrict__ C, u16* __restrict__ Cb,
    int ldc, int M, int N, int K) {
  constexpr int MF = (TILE == 128) ? 4 : 2;
  constexpr int TB = TILE * 32;
  constexpr int NLD = (TILE == 128) ? 4 : 2;
  __shared__ u16 As[2][TB], Ws[2][TB];
  int bid = blockIdx.x;
  if (SWZ) {
    int nwg = gridDim.x;
    int q = nwg >> 3, r = nwg & 7;
    int xcd = bid & 7, li = bid >> 3;
    bid = (xcd < r ? xcd * (q + 1) : r * (q + 1) + (xcd - r) * q) + li;
  }
  int bm, bn;
  if (TILE == 128) { bm = (bid & 31) << 7; bn = (bid >> 5) << 7; }
  else             { bm = (bid & 63) << 6; bn = (bid >> 6) << 6; }
  int t = threadIdx.x, lane = t & 63, wave = t >> 6;
  int wm0, wn0;
  if (TILE == 128) { wm0 = (wave >> 1) << 6; wn0 = (wave & 1) << 6; }
  else             { wm0 = (wave >> 1) << 5; wn0 = (wave & 1) << 5; }
  int fr = lane & 15, fk = (lane >> 4) << 3;
  int r0 = t >> 2, sl = (t & 3) << 3;
  const u16* gA0 = A + (size_t)(bm + r0) * lda + sl;
  const u16* gA1 = gA0 + (size_t)64 * lda;
  int n0 = bn + r0;      if (n0 > N - 1) n0 = N - 1;
  int n1 = bn + r0 + 64; if (n1 > N - 1) n1 = N - 1;
  const u16* gW0 = W + (size_t)n0 * ldw + sl;
  const u16* gW1 = W + (size_t)n1 * ldw + sl;
  f32x4 acc[MF][MF] = {};
  int nk = K >> 5;
  auto stage = [&](int buf, int k0) {
    gload16(gA0 + k0, As[buf] + t * 8);
    gload16(gW0 + k0, Ws[buf] + t * 8);
    if (TILE == 128) {
      gload16(gA1 + k0, As[buf] + t * 8 + 2048);
      gload16(gW1 + k0, Ws[buf] + t * 8 + 2048);
    }
  };
  stage(0, 0);
  for (int s = 0; s < nk; ++s) {
    int cur = s & 1;
    if (s + 1 < nk) {
      stage(cur ^ 1, (s + 1) << 5);
      asm volatile("s_waitcnt vmcnt(%0)" :: "i"(NLD) : "memory");
    } else {
      asm volatile("s_waitcnt vmcnt(0)" ::: "memory");
    }
    __builtin_amdgcn_sched_barrier(0);
    __builtin_amdgcn_s_barrier();
    __builtin_amdgcn_sched_barrier(0);
    short8 af[MF], wf[MF];
#pragma unroll
    for (int mi = 0; mi < MF; ++mi) af[mi] = *(const short8*)&As[cur][(wm0 + mi * 16 + fr) * 32 + fk];
#pragma unroll
    for (int ni = 0; ni < MF; ++ni) wf[ni] = *(const short8*)&Ws[cur][(wn0 + ni * 16 + fr) * 32 + fk];
#pragma unroll
    for (int mi = 0; mi < MF; ++mi)
#pragma unroll
      for (int ni = 0; ni < MF; ++ni)
        acc[mi][ni] = __builtin_amdgcn_mfma_f32_16x16x32_bf16(af[mi], wf[ni], acc[mi][ni], 0, 0, 0);
    __builtin_amdgcn_sched_barrier(0);
    __builtin_amdgcn_s_barrier();
  }
  int frow = (lane >> 4) << 2;
#pragma unroll
  for (int ni = 0; ni < MF; ++ni) {
    int col = bn + wn0 + ni * 16 + fr;
    if (col < N) {
      float bv = BIAS ? bias[col] : 0.f;
#pragma unroll
      for (int mi = 0; mi < MF; ++mi) {
        int row = bm + wm0 + mi * 16 + frow;
#pragma unroll
        for (int rr = 0; rr < 4; ++rr) {
          float v = acc[mi][ni][rr] + bv;
          if (ACT == 1) v = (v > 20.f) ? v : log1pf(__expf(v));
          size_t o = (size_t)(row + rr) * ldc + col;
          if (OUTB == 0) C[o] = v;
          else if (OUTB == 1) Cb[o] = f2bf(v);
          else { C[o] = v; Cb[o] = f2bf(v); }
        }
      }
    }
  }
}

// ---------------- final GEMM v7 (r12 best): write-local + counted-vmcnt + NT epilogue ----
__global__ __launch_bounds__(256, 4) void k_gemmF(
    const u16* __restrict__ A, const u16* __restrict__ W,
    const float* __restrict__ bias, float* __restrict__ C,
    int ldc, int N) {
  __shared__ __align__(16) char smraw[40960];   // union: As/Ws dbuf | Cs chunk
  u16* As = (u16*)smraw;                        // [2][64*32]
  u16* Ws = (u16*)(smraw + 8192);               // [2][256*32]
  float* Cs = (float*)smraw;                    // [32][260] f32 epilogue
  int bid = blockIdx.x;
  {
    int nwg = gridDim.x;
    int q = nwg >> 3, r = nwg & 7;
    int xcd = bid & 7, li = bid >> 3;
    bid = (xcd < r ? xcd * (q + 1) : r * (q + 1) + (xcd - r) * q) + li;
  }
  int mg = bid / 1576;                // 1576 = 197 * 8; write-local: mi innermost
  int rem = bid - mg * 1576;
  int np = rem >> 3, mi = rem & 7;
  int bm = ((mg << 3) + mi) << 6;
  int bn = np << 8;
  int t = threadIdx.x, lane = t & 63, wave = t >> 6;
  int wm0 = (wave >> 1) << 5;
  int wn0 = (wave & 1) << 7;
  int fr = lane & 15, hi = lane >> 4, fk = hi << 3;
  int r0 = t >> 2, sl = (t & 3) << 3;
  const u16* gA = A + (size_t)(bm + r0) * 384 + sl;
  int nrow[4];
#pragma unroll
  for (int i = 0; i < 4; ++i) {
    int gn = bn + r0 + i * 64;
    nrow[i] = (gn > N - 1) ? (N - 1) : gn;
  }
  const u16* gWs = W + sl;
  f32x4 acc[2][8] = {};
  auto stage = [&](int buf, int k0) {
    gload16(gA + k0, As + buf * 2048 + t * 8);
#pragma unroll
    for (int i = 0; i < 4; ++i)
      gload16(gWs + (size_t)nrow[i] * 384 + k0, Ws + buf * 8192 + t * 8 + i * 2048);
  };
  stage(0, 0);
  for (int s = 0; s < 12; ++s) {
    int cur = s & 1;
    if (s + 1 < 12) {
      stage(cur ^ 1, (s + 1) << 5);
      asm volatile("s_waitcnt vmcnt(5)" ::: "memory");
    } else {
      asm volatile("s_waitcnt vmcnt(0)" ::: "memory");
    }
    __builtin_amdgcn_sched_barrier(0);
    __builtin_amdgcn_s_barrier();
    __builtin_amdgcn_sched_barrier(0);
    short8 af[2];
#pragma unroll
    for (int mi2 = 0; mi2 < 2; ++mi2)
      af[mi2] = *(const short8*)&As[cur * 2048 + (wm0 + mi2 * 16 + fr) * 32 + fk];
#pragma unroll
    for (int ni = 0; ni < 8; ++ni) {
      short8 wf = *(const short8*)&Ws[cur * 8192 + (wn0 + ni * 16 + fr) * 32 + fk];
#pragma unroll
      for (int mi2 = 0; mi2 < 2; ++mi2)
        acc[mi2][ni] = __builtin_amdgcn_mfma_f32_16x16x32_bf16(af[mi2], wf, acc[mi2][ni], 0, 0, 0);
    }
    __builtin_amdgcn_sched_barrier(0);
    __builtin_amdgcn_s_barrier();
  }
  int cq = (t & 63) << 2;
  int gcol0 = bn + cq;
  f4 bv4;
  if (gcol0 + 3 < N) bv4 = *(const f4*)&bias[gcol0];
  else {
#pragma unroll
    for (int e = 0; e < 4; ++e) bv4[e] = (gcol0 + e < N) ? bias[gcol0 + e] : 0.f;
  }
  int frow = hi << 2;
#pragma unroll
  for (int c = 0; c < 2; ++c) {
    if (c) __syncthreads();
    if (wm0 == c * 32) {
#pragma unroll
      for (int ni = 0; ni < 8; ++ni) {
        int lc = wn0 + ni * 16 + fr;
#pragma unroll
        for (int mi2 = 0; mi2 < 2; ++mi2)
#pragma unroll
          for (int rr = 0; rr < 4; ++rr)
            Cs[(mi2 * 16 + frow + rr) * 260 + lc] = acc[mi2][ni][rr];
      }
    }
    __syncthreads();
#pragma unroll
    for (int p = 0; p < 8; ++p) {
      int lr = (p << 2) + (t >> 6);
      f4 v = *(const f4*)&Cs[lr * 260 + cq];
      v += bv4;
      float* cp = C + (size_t)(bm + c * 32 + lr) * ldc + gcol0;
      if (gcol0 + 3 < N) {
        __builtin_nontemporal_store(v, (f4*)cp);
      } else {
#pragma unroll
        for (int e = 0; e < 4; ++e)
          if (gcol0 + e < N) __builtin_nontemporal_store(v[e], cp + e);
      }
    }
  }
}

// ---------------- segmented selective scan: 4 ch-groups per 256-thread block ----------
DEV int scan_ch0_w(int g, int w) { return (((g & 7) * 24) + ((g >> 3) << 2) + w) * 4; }

DEV void dt_inline(const float* __restrict__ xdbl, size_t rowbase, int lane,
                   const float* __restrict__ s_w, const float* __restrict__ s_b,
                   float (*s_dt)[4]) {
  const float* xr = xdbl + (rowbase + lane) * 56;
  f4 x0 = *(const f4*)xr,        x1 = *(const f4*)(xr + 4),  x2 = *(const f4*)(xr + 8);
  f4 x3 = *(const f4*)(xr + 12), x4 = *(const f4*)(xr + 16), x5 = *(const f4*)(xr + 20);
#pragma unroll
  for (int cc = 0; cc < 4; ++cc) {
    const float* w = s_w + cc * 24;
    float acc = s_b[cc];
#pragma unroll
    for (int q = 0; q < 4; ++q) acc = fmaf(x0[q], w[q], acc);
#pragma unroll
    for (int q = 0; q < 4; ++q) acc = fmaf(x1[q], w[4 + q], acc);
#pragma unroll
    for (int q = 0; q < 4; ++q) acc = fmaf(x2[q], w[8 + q], acc);
#pragma unroll
    for (int q = 0; q < 4; ++q) acc = fmaf(x3[q], w[12 + q], acc);
#pragma unroll
    for (int q = 0; q < 4; ++q) acc = fmaf(x4[q], w[16 + q], acc);
#pragma unroll
    for (int q = 0; q < 4; ++q) acc = fmaf(x5[q], w[20 + q], acc);
    s_dt[lane][cc] = (acc > 20.f) ? acc : log1pf(__expf(acc));
  }
}

__global__ __launch_bounds__(256) void k_scanA(
    const float* __restrict__ xdbl, const float* __restrict__ xi,
    const float* __restrict__ A_log,
    const float* __restrict__ dtw, const float* __restrict__ dtbias,
    float* __restrict__ Hloc, float* __restrict__ Sdt) {
  __shared__ float s_dt[4][64][4], s_w[4][96], s_b[4][4];
  int b = blockIdx.y, seg = blockIdx.z;
  int tid = threadIdx.x, w = tid >> 6, lane = tid & 63;
  int ch0 = scan_ch0_w(blockIdx.x, w);
  int c = lane >> 4, n = lane & 15;
  int d = ch0 + c;
  for (int i = lane; i < 96; i += 64) s_w[w][i] = dtw[ch0 * 24 + i];
  if (lane < 4) s_b[w][lane] = dtbias[ch0 + lane];
  size_t rowbase = (size_t)b * 2048 + seg * 64;
  __syncthreads();
  dt_inline(xdbl, rowbase, lane, s_w[w], s_b[w], s_dt[w]);
  __syncthreads();
  float a = -__expf(A_log[d * 16 + n]);
  float h = 0.f, sdt = 0.f;
  size_t row = rowbase;
#pragma unroll 4
  for (int i = 0; i < 64; ++i, ++row) {
    float dtv = s_dt[w][i][c];
    float xiv = xi[row * 768 + d];
    float Bv = xdbl[row * 56 + 24 + n];
    float da = __expf(dtv * a);
    h = fmaf(da, h, dtv * Bv * xiv);
    sdt += dtv;
  }
  size_t o = (((size_t)b * 32 + seg) * 768 + d) * 16 + n;
  Hloc[o] = h;
  if (n == 0) Sdt[((size_t)b * 32 + seg) * 768 + d] = sdt;
}

__global__ __launch_bounds__(256) void k_scanC(
    const float* __restrict__ xdbl, const float* __restrict__ xi,
    const float* __restrict__ xz, const float* __restrict__ A_log,
    const float* __restrict__ Dp,
    const float* __restrict__ dtw, const float* __restrict__ dtbias,
    const float* __restrict__ Hloc, const float* __restrict__ Sdt,
    u16* __restrict__ y) {
  __shared__ float s_dt[4][64][4], s_y[4][64][4], s_w[4][96], s_b[4][4];
  int b = blockIdx.y, seg = blockIdx.z;
  int tid = threadIdx.x, w = tid >> 6, lane = tid & 63;
  int ch0 = scan_ch0_w(blockIdx.x, w);
  int c = lane >> 4, n = lane & 15;
  int d = ch0 + c;
  for (int i = lane; i < 96; i += 64) s_w[w][i] = dtw[ch0 * 24 + i];
  if (lane < 4) s_b[w][lane] = dtbias[ch0 + lane];
  size_t rowbase = (size_t)b * 2048 + seg * 64;
  __syncthreads();
  dt_inline(xdbl, rowbase, lane, s_w[w], s_b[w], s_dt[w]);
  float a = -__expf(A_log[d * 16 + n]);
  float h = 0.f;
  for (int s = 0; s < seg; ++s) {
    float P = __expf(a * Sdt[((size_t)b * 32 + s) * 768 + d]);
    h = fmaf(P, h, Hloc[(((size_t)b * 32 + s) * 768 + d) * 16 + n]);
  }
  __syncthreads();
  size_t row = rowbase;
#pragma unroll 2
  for (int i = 0; i < 64; ++i, ++row) {
    float dtv = s_dt[w][i][c];
    float xiv = xi[row * 768 + d];
    float Bv = xdbl[row * 56 + 24 + n];
    float Cv = xdbl[row * 56 + 40 + n];
    float da = __expf(dtv * a);
    h = fmaf(da, h, dtv * Bv * xiv);
    float yv = h * Cv;
    yv += __shfl_xor(yv, 1);
    yv += __shfl_xor(yv, 2);
    yv += __shfl_xor(yv, 4);
    yv += __shfl_xor(yv, 8);
    if (n == 0) s_y[w][i][c] = yv;
  }
  __syncthreads();
  size_t rw = rowbase + lane;
  f4 xiv4 = *(const f4*)(xi + rw * 768 + ch0);
  f4 dpv = *(const f4*)(Dp + ch0);
  f4 zv = *(const f4*)(xz + rw * 1536 + 768 + ch0);
  u16x4 ob;
#pragma unroll
  for (int e = 0; e < 4; ++e) {
    float o = (s_y[w][lane][e] + xiv4[e] * dpv[e]) * siluf(zv[e]);
    ob[e] = f2bf(o);
  }
  *(u16x4*)(y + rw * 768 + ch0) = ob;
}

// =====================================================================================
extern "C" void kernel_launch(void* const* d_in, const int* in_sizes, int n_in,
                              void* d_out, int out_size, void* d_ws, size_t ws_size,
                              hipStream_t stream) {
  const float* audio   = (const float*)d_in[0];
  const int*   tokens  = (const int*)d_in[1];
  const float* conv1_w = (const float*)d_in[2];
  const float* conv1_b = (const float*)d_in[3];
  const float* conv2_w = (const float*)d_in[4];
  const float* conv2_b = (const float*)d_in[5];
  const float* embedw  = (const float*)d_in[6];
  const float* P1[9], *P2[9];
  for (int i = 0; i < 9; ++i) { P1[i] = (const float*)d_in[7 + i]; P2[i] = (const float*)d_in[16 + i]; }
  const float* proj_w = (const float*)d_in[25];
  const float* proj_b = (const float*)d_in[26];
  (void)in_sizes; (void)n_in; (void)out_size; (void)ws_size;

  // ---- arena in d_out (fully overwritten by final GEMM) ----
  float* base = (float*)d_out;
  size_t off = 0;
  auto af = [&](size_t n) { float* p = base + off; off += n; return p; };
  float* xz   = af((size_t)4096 * 1536);
  float* xif  = af((size_t)4096 * 768);
  float* xdbl = af((size_t)4096 * 56);
  float* a1t  = af((size_t)2 * 1024 * 192);
  float* w1t  = af((size_t)80 * 3 * 192);
  float* w2t  = af((size_t)192 * 3 * 384);
  float* Hloc = af((size_t)2 * 32 * 768 * 16);
  float* Sdt  = af((size_t)2 * 32 * 768);
  u16* ub = (u16*)(base + off);
  size_t uoff = 0;
  auto au = [&](size_t n) { u16* p = ub + uoff; uoff += n; return p; };
  u16* Xin_b  = au((size_t)4096 * 384);
  u16* Xmid_b = au((size_t)4096 * 384);
  u16* yb16   = au((size_t)4096 * 768);
  u16* Wi1 = au((size_t)1536 * 384);
  u16* Wx1 = au((size_t)56 * 768);
  u16* Wo1 = au((size_t)384 * 768);
  u16* Wi2 = au((size_t)1536 * 384);
  u16* Wx2 = au((size_t)56 * 768);
  u16* Wo2 = au((size_t)384 * 768);
  u16* X2b    = (u16*)d_ws;                       // survive final GEMM's d_out writes
  u16* projwb = X2b + (size_t)4096 * 384;

  // ---- one batched weight-convert kernel (7 plain segments) ----
  CvtArgs ca;
  const float* srcs[7] = {P1[0], P1[3], P1[8], P2[0], P2[3], P2[8], proj_w};
  u16* dsts[7] = {Wi1, Wx1, Wo1, Wi2, Wx2, Wo2, projwb};
  int nqs[7] = {147456, 10752, 73728, 147456, 10752, 73728, 4824672};
  int cum = 0;
  for (int j = 0; j < 7; ++j) {
    ca.src[j] = srcs[j]; ca.dst[j] = dsts[j]; ca.nq[j] = nqs[j];
    ca.bstart[j] = cum; cum += (nqs[j] + 255) / 256;
  }
  ca.bstart[7] = cum;
  k_cvtmulti<<<dim3(cum), dim3(256), 0, stream>>>(ca);

  // ---- audio frontend + embedding -> Xin_b bf16 ----
  k_wtrans<<<dim3(180), dim3(256), 0, stream>>>(conv1_w, w1t, 192, 80);
  k_wtrans<<<dim3(864), dim3(256), 0, stream>>>(conv2_w, w2t, 384, 192);
  k_conv1<<<dim3(128), dim3(192), 0, stream>>>(audio, w1t, conv1_b, a1t);
  k_conv2b<<<dim3(256), dim3(384), 0, stream>>>(a1t, w2t, conv2_b, Xin_b);
  k_embedb<<<dim3(768), dim3(256), 0, stream>>>(tokens, embedw, Xin_b);

  auto run_mamba = [&](const float* const* P, const u16* Xin, u16* Xout,
                       const u16* Wi, const u16* Wx, const u16* Wo) {
    k_gemm2<64, 0, 0, 0, 1><<<dim3(64 * 24), dim3(256), 0, stream>>>(
        Xin, 384, Wi, 384, nullptr, xz, nullptr, 1536, 4096, 1536, 384);
    k_dwx<<<dim3(256), dim3(256), 0, stream>>>(xz, P[1], P[2], Wx, xif, xdbl);
    k_scanA<<<dim3(48, 2, 32), dim3(256), 0, stream>>>(
        xdbl, xif, P[6], P[4], P[5], Hloc, Sdt);
    k_scanC<<<dim3(48, 2, 32), dim3(256), 0, stream>>>(
        xdbl, xif, xz, P[6], P[7], P[4], P[5], Hloc, Sdt, yb16);
    k_gemm2<64, 0, 0, 1, 0><<<dim3(64 * 6), dim3(256), 0, stream>>>(
        yb16, 768, Wo, 768, nullptr, nullptr, Xout, 384, 4096, 384, 768);
  };
  run_mamba(P1, Xin_b, Xmid_b, Wi1, Wx1, Wo1);
  run_mamba(P2, Xmid_b, X2b, Wi2, Wx2, Wo2);

  // ---- final projection -> d_out [4096, 50257] f32 (v7: counted-vmcnt pipeline) ----
  k_gemmF<<<dim3(64 * 197), dim3(256), 0, stream>>>(
      X2b, projwb, proj_b, (float*)d_out, 50257, 50257);
}

// Round 18
// 625.301 us; speedup vs baseline: 1.0044x; 1.0044x over previous
//
#include <hip/hip_runtime.h>

typedef unsigned short u16;
typedef __attribute__((ext_vector_type(4))) float f4;
typedef __attribute__((ext_vector_type(4))) float f32x4;
typedef __attribute__((ext_vector_type(8))) short short8;
typedef __attribute__((ext_vector_type(4))) unsigned short u16x4;

#define DEV static __device__ __forceinline__

DEV u16 f2bf(float f) {                    // round-to-nearest-even f32->bf16
  unsigned u = __float_as_uint(f);
  u += 0x7fffu + ((u >> 16) & 1u);
  return (u16)(u >> 16);
}
DEV float siluf(float z) { return z / (1.f + __expf(-z)); }

// async global->LDS, 16B per lane (wave-uniform LDS base + lane*16)
DEV void gload16(const u16* g, const u16* l) {
  __builtin_amdgcn_global_load_lds(
      (const __attribute__((address_space(1))) unsigned int*)(unsigned long long)g,
      (__attribute__((address_space(3))) unsigned int*)(unsigned int)(unsigned long long)l,
      16, 0, 0);
}

// ---------------- batched weight converts (6 mamba weights + proj_w) ----------------
struct CvtArgs {
  const float* src[7];
  u16* dst[7];
  int bstart[8];
  int nq[7];
};

DEV void cvt_plain(const float* __restrict__ s, u16* __restrict__ d, int q, int nq) {
  if (q < nq) {
    f4 v = ((const f4*)s)[q];
    u16x4 o;
#pragma unroll
    for (int e = 0; e < 4; ++e) o[e] = f2bf(v[e]);
    ((u16x4*)d)[q] = o;
  }
}

__global__ void k_cvtmulti(CvtArgs a) {
  int b = blockIdx.x;
  int i = 0;
#pragma unroll
  for (int j = 1; j < 7; ++j) i += (b >= a.bstart[j]);
#pragma unroll
  for (int j = 0; j < 7; ++j) {
    if (i == j)
      cvt_plain(a.src[j], a.dst[j], (b - a.bstart[j]) * 256 + threadIdx.x, a.nq[j]);
  }
}

// ---------------- conv weight transpose [O][I][3] -> [I][3][O] ----------------
__global__ void k_wtrans(const float* __restrict__ in, float* __restrict__ out, int O, int I) {
  int n = O * I * 3;
  for (int g = blockIdx.x * blockDim.x + threadIdx.x; g < n; g += gridDim.x * blockDim.x) {
    int o = g / (I * 3);
    int rem = g - o * (I * 3);
    out[rem * O + o] = in[g];
  }
}

// ---------------- audio conv1: [2,80,1024] -> relu -> a1t [2,1024,192] ----------------
__global__ __launch_bounds__(192) void k_conv1(const float* __restrict__ audio,
    const float* __restrict__ w1t, const float* __restrict__ b1, float* __restrict__ a1t) {
  __shared__ float s[80][18];
  int bx = blockIdx.x;
  int b = bx >> 6, l0 = (bx & 63) << 4;
  int tid = threadIdx.x;
  for (int i = tid; i < 80 * 18; i += 192) {
    int ci = i / 18, dl = i - ci * 18;
    int l = l0 + dl - 1;
    s[ci][dl] = (l >= 0 && l < 1024) ? audio[(b * 80 + ci) * 1024 + l] : 0.f;
  }
  __syncthreads();
  int co = tid;
  float acc[16];
  float bias = b1[co];
#pragma unroll
  for (int i = 0; i < 16; ++i) acc[i] = bias;
  for (int ci = 0; ci < 80; ++ci) {
#pragma unroll
    for (int j = 0; j < 3; ++j) {
      float w = w1t[(ci * 3 + j) * 192 + co];
#pragma unroll
      for (int ls = 0; ls < 16; ++ls) acc[ls] = fmaf(s[ci][ls + j], w, acc[ls]);
    }
  }
#pragma unroll
  for (int ls = 0; ls < 16; ++ls) {
    float v = acc[ls] > 0.f ? acc[ls] : 0.f;
    a1t[(b * 1024 + l0 + ls) * 192 + co] = v;
  }
}

// ---------------- audio conv2: a1t -> bf16 X rows [b*2048 + l][384] ----------------
__global__ __launch_bounds__(384) void k_conv2b(const float* __restrict__ a1t,
    const float* __restrict__ w2t, const float* __restrict__ b2, u16* __restrict__ Xb) {
  __shared__ float s[10][192];
  int bx = blockIdx.x;
  int b = bx >> 7, l0 = (bx & 127) << 3;
  int tid = threadIdx.x;
  for (int i = tid; i < 10 * 192; i += 384) {
    int dl = i / 192, ci = i - dl * 192;
    int l = l0 + dl - 1;
    s[dl][ci] = (l >= 0 && l < 1024) ? a1t[(b * 1024 + l) * 192 + ci] : 0.f;
  }
  __syncthreads();
  int co = tid;
  float acc[8];
  float bias = b2[co];
#pragma unroll
  for (int i = 0; i < 8; ++i) acc[i] = bias;
  for (int ci = 0; ci < 192; ++ci) {
#pragma unroll
    for (int j = 0; j < 3; ++j) {
      float w = w2t[(ci * 3 + j) * 384 + co];
#pragma unroll
      for (int ls = 0; ls < 8; ++ls) acc[ls] = fmaf(s[ls + j][ci], w, acc[ls]);
    }
  }
#pragma unroll
  for (int ls = 0; ls < 8; ++ls)
    Xb[((size_t)(b * 2048 + l0 + ls)) * 384 + co] = f2bf(acc[ls]);
}

// ---------------- text embedding gather -> bf16 X rows [b*2048+1024+t] ----------------
__global__ void k_embedb(const int* __restrict__ tok, const float* __restrict__ emb,
                         u16* __restrict__ Xb) {
  int gid = blockIdx.x * blockDim.x + threadIdx.x;
  if (gid >= 2 * 1024 * 96) return;
  int q = gid % 96;
  int rt = gid / 96;
  int b = rt >> 10, t = rt & 1023;
  int tk = tok[b * 1024 + t];
  f4 v = *(const f4*)(emb + (size_t)tk * 384 + q * 4);
  u16x4 o;
#pragma unroll
  for (int e = 0; e < 4; ++e) o[e] = f2bf(v[e]);
  *(u16x4*)(Xb + ((size_t)(b * 2048 + 1024 + t)) * 384 + q * 4) = o;
}

// ---------------- depthwise causal conv (K=4) + silu: dual f32+bf16 output ----------------
__global__ void k_dwconv2(const float* __restrict__ xz, const float* __restrict__ cw,
                          const float* __restrict__ cb, float* __restrict__ xif,
                          u16* __restrict__ xib) {
  int gid = blockIdx.x * blockDim.x + threadIdx.x;
  if (gid >= 4096 * 192) return;
  int d4 = gid % 192;
  int row = gid / 192;
  int b = row >> 11, l = row & 2047;
  int d = d4 * 4;
  f4 cw0 = *(const f4*)(cw + d * 4);
  f4 cw1 = *(const f4*)(cw + d * 4 + 4);
  f4 cw2 = *(const f4*)(cw + d * 4 + 8);
  f4 cw3 = *(const f4*)(cw + d * 4 + 12);
  f4 acc = *(const f4*)(cb + d);
#pragma unroll
  for (int j = 0; j < 4; ++j) {
    int lj = l - 3 + j;
    if (lj >= 0) {
      f4 v = *(const f4*)(xz + ((size_t)(b * 2048 + lj)) * 1536 + d);
      acc[0] = fmaf(v[0], cw0[j], acc[0]);
      acc[1] = fmaf(v[1], cw1[j], acc[1]);
      acc[2] = fmaf(v[2], cw2[j], acc[2]);
      acc[3] = fmaf(v[3], cw3[j], acc[3]);
    }
  }
  f4 o;
  u16x4 ob;
#pragma unroll
  for (int e = 0; e < 4; ++e) { o[e] = siluf(acc[e]); ob[e] = f2bf(o[e]); }
  *(f4*)(xif + (size_t)row * 768 + d) = o;
  *(u16x4*)(xib + (size_t)row * 768 + d) = ob;
}

// ---------------- bf16 MFMA GEMM: 2-buffer LDS + counted-vmcnt pipeline (T4) ----------------
template <int TILE, int BIAS, int ACT, int OUTB, int SWZ>
__global__ __launch_bounds__(256) void k_gemm2(
    const u16* __restrict__ A, int lda, const u16* __restrict__ W, int ldw,
    const float* __restrict__ bias, float* __restrict__ C, u16* __restrict__ Cb,
    int ldc, int M, int N, int K) {
  constexpr int MF = (TILE == 128) ? 4 : 2;
  constexpr int TB = TILE * 32;
  constexpr int NLD = (TILE == 128) ? 4 : 2;
  __shared__ u16 As[2][TB], Ws[2][TB];
  int bid = blockIdx.x;
  if (SWZ) {
    int nwg = gridDim.x;
    int q = nwg >> 3, r = nwg & 7;
    int xcd = bid & 7, li = bid >> 3;
    bid = (xcd < r ? xcd * (q + 1) : r * (q + 1) + (xcd - r) * q) + li;
  }
  int bm, bn;
  if (TILE == 128) { bm = (bid & 31) << 7; bn = (bid >> 5) << 7; }
  else             { bm = (bid & 63) << 6; bn = (bid >> 6) << 6; }
  int t = threadIdx.x, lane = t & 63, wave = t >> 6;
  int wm0, wn0;
  if (TILE == 128) { wm0 = (wave >> 1) << 6; wn0 = (wave & 1) << 6; }
  else             { wm0 = (wave >> 1) << 5; wn0 = (wave & 1) << 5; }
  int fr = lane & 15, fk = (lane >> 4) << 3;
  int r0 = t >> 2, sl = (t & 3) << 3;
  const u16* gA0 = A + (size_t)(bm + r0) * lda + sl;
  const u16* gA1 = gA0 + (size_t)64 * lda;
  int n0 = bn + r0;      if (n0 > N - 1) n0 = N - 1;
  int n1 = bn + r0 + 64; if (n1 > N - 1) n1 = N - 1;
  const u16* gW0 = W + (size_t)n0 * ldw + sl;
  const u16* gW1 = W + (size_t)n1 * ldw + sl;
  f32x4 acc[MF][MF] = {};
  int nk = K >> 5;
  auto stage = [&](int buf, int k0) {
    gload16(gA0 + k0, As[buf] + t * 8);
    gload16(gW0 + k0, Ws[buf] + t * 8);
    if (TILE == 128) {
      gload16(gA1 + k0, As[buf] + t * 8 + 2048);
      gload16(gW1 + k0, Ws[buf] + t * 8 + 2048);
    }
  };
  stage(0, 0);
  for (int s = 0; s < nk; ++s) {
    int cur = s & 1;
    if (s + 1 < nk) {
      stage(cur ^ 1, (s + 1) << 5);
      asm volatile("s_waitcnt vmcnt(%0)" :: "i"(NLD) : "memory");
    } else {
      asm volatile("s_waitcnt vmcnt(0)" ::: "memory");
    }
    __builtin_amdgcn_sched_barrier(0);
    __builtin_amdgcn_s_barrier();
    __builtin_amdgcn_sched_barrier(0);
    short8 af[MF], wf[MF];
#pragma unroll
    for (int mi = 0; mi < MF; ++mi) af[mi] = *(const short8*)&As[cur][(wm0 + mi * 16 + fr) * 32 + fk];
#pragma unroll
    for (int ni = 0; ni < MF; ++ni) wf[ni] = *(const short8*)&Ws[cur][(wn0 + ni * 16 + fr) * 32 + fk];
#pragma unroll
    for (int mi = 0; mi < MF; ++mi)
#pragma unroll
      for (int ni = 0; ni < MF; ++ni)
        acc[mi][ni] = __builtin_amdgcn_mfma_f32_16x16x32_bf16(af[mi], wf[ni], acc[mi][ni], 0, 0, 0);
    __builtin_amdgcn_sched_barrier(0);
    __builtin_amdgcn_s_barrier();
  }
  int frow = (lane >> 4) << 2;
#pragma unroll
  for (int ni = 0; ni < MF; ++ni) {
    int col = bn + wn0 + ni * 16 + fr;
    if (col < N) {
      float bv = BIAS ? bias[col] : 0.f;
#pragma unroll
      for (int mi = 0; mi < MF; ++mi) {
        int row = bm + wm0 + mi * 16 + frow;
#pragma unroll
        for (int rr = 0; rr < 4; ++rr) {
          float v = acc[mi][ni][rr] + bv;
          if (ACT == 1) v = (v > 20.f) ? v : log1pf(__expf(v));
          size_t o = (size_t)(row + rr) * ldc + col;
          if (OUTB == 0) C[o] = v;
          else if (OUTB == 1) Cb[o] = f2bf(v);
          else { C[o] = v; Cb[o] = f2bf(v); }
        }
      }
    }
  }
}

// ---------------- final GEMM v7 (r12 best): write-local + counted-vmcnt + NT epilogue ----
__global__ __launch_bounds__(256, 4) void k_gemmF(
    const u16* __restrict__ A, const u16* __restrict__ W,
    const float* __restrict__ bias, float* __restrict__ C,
    int ldc, int N) {
  __shared__ __align__(16) char smraw[40960];   // union: As/Ws dbuf | Cs chunk
  u16* As = (u16*)smraw;                        // [2][64*32]
  u16* Ws = (u16*)(smraw + 8192);               // [2][256*32]
  float* Cs = (float*)smraw;                    // [32][260] f32 epilogue
  int bid = blockIdx.x;
  {
    int nwg = gridDim.x;
    int q = nwg >> 3, r = nwg & 7;
    int xcd = bid & 7, li = bid >> 3;
    bid = (xcd < r ? xcd * (q + 1) : r * (q + 1) + (xcd - r) * q) + li;
  }
  int mg = bid / 1576;                // 1576 = 197 * 8; write-local: mi innermost
  int rem = bid - mg * 1576;
  int np = rem >> 3, mi = rem & 7;
  int bm = ((mg << 3) + mi) << 6;
  int bn = np << 8;
  int t = threadIdx.x, lane = t & 63, wave = t >> 6;
  int wm0 = (wave >> 1) << 5;
  int wn0 = (wave & 1) << 7;
  int fr = lane & 15, hi = lane >> 4, fk = hi << 3;
  int r0 = t >> 2, sl = (t & 3) << 3;
  const u16* gA = A + (size_t)(bm + r0) * 384 + sl;
  int nrow[4];
#pragma unroll
  for (int i = 0; i < 4; ++i) {
    int gn = bn + r0 + i * 64;
    nrow[i] = (gn > N - 1) ? (N - 1) : gn;
  }
  const u16* gWs = W + sl;
  f32x4 acc[2][8] = {};
  auto stage = [&](int buf, int k0) {
    gload16(gA + k0, As + buf * 2048 + t * 8);
#pragma unroll
    for (int i = 0; i < 4; ++i)
      gload16(gWs + (size_t)nrow[i] * 384 + k0, Ws + buf * 8192 + t * 8 + i * 2048);
  };
  stage(0, 0);
  for (int s = 0; s < 12; ++s) {
    int cur = s & 1;
    if (s + 1 < 12) {
      stage(cur ^ 1, (s + 1) << 5);
      asm volatile("s_waitcnt vmcnt(5)" ::: "memory");
    } else {
      asm volatile("s_waitcnt vmcnt(0)" ::: "memory");
    }
    __builtin_amdgcn_sched_barrier(0);
    __builtin_amdgcn_s_barrier();
    __builtin_amdgcn_sched_barrier(0);
    short8 af[2];
#pragma unroll
    for (int mi2 = 0; mi2 < 2; ++mi2)
      af[mi2] = *(const short8*)&As[cur * 2048 + (wm0 + mi2 * 16 + fr) * 32 + fk];
#pragma unroll
    for (int ni = 0; ni < 8; ++ni) {
      short8 wf = *(const short8*)&Ws[cur * 8192 + (wn0 + ni * 16 + fr) * 32 + fk];
#pragma unroll
      for (int mi2 = 0; mi2 < 2; ++mi2)
        acc[mi2][ni] = __builtin_amdgcn_mfma_f32_16x16x32_bf16(af[mi2], wf, acc[mi2][ni], 0, 0, 0);
    }
    __builtin_amdgcn_sched_barrier(0);
    __builtin_amdgcn_s_barrier();
  }
  int cq = (t & 63) << 2;
  int gcol0 = bn + cq;
  f4 bv4;
  if (gcol0 + 3 < N) bv4 = *(const f4*)&bias[gcol0];
  else {
#pragma unroll
    for (int e = 0; e < 4; ++e) bv4[e] = (gcol0 + e < N) ? bias[gcol0 + e] : 0.f;
  }
  int frow = hi << 2;
#pragma unroll
  for (int c = 0; c < 2; ++c) {
    if (c) __syncthreads();
    if (wm0 == c * 32) {
#pragma unroll
      for (int ni = 0; ni < 8; ++ni) {
        int lc = wn0 + ni * 16 + fr;
#pragma unroll
        for (int mi2 = 0; mi2 < 2; ++mi2)
#pragma unroll
          for (int rr = 0; rr < 4; ++rr)
            Cs[(mi2 * 16 + frow + rr) * 260 + lc] = acc[mi2][ni][rr];
      }
    }
    __syncthreads();
#pragma unroll
    for (int p = 0; p < 8; ++p) {
      int lr = (p << 2) + (t >> 6);
      f4 v = *(const f4*)&Cs[lr * 260 + cq];
      v += bv4;
      float* cp = C + (size_t)(bm + c * 32 + lr) * ldc + gcol0;
      if (gcol0 + 3 < N) {
        __builtin_nontemporal_store(v, (f4*)cp);
      } else {
#pragma unroll
        for (int e = 0; e < 4; ++e)
          if (gcol0 + e < N) __builtin_nontemporal_store(v[e], cp + e);
      }
    }
  }
}

// ---------------- segmented selective scan: 4 ch-groups per 256-thread block ----------
DEV int scan_ch0_w(int g, int w) { return (((g & 7) * 24) + ((g >> 3) << 2) + w) * 4; }

DEV void dt_inline(const float* __restrict__ xdbl, size_t rowbase, int lane,
                   const float* __restrict__ s_w, const float* __restrict__ s_b,
                   float (*s_dt)[4]) {
  const float* xr = xdbl + (rowbase + lane) * 56;
  f4 x0 = *(const f4*)xr,        x1 = *(const f4*)(xr + 4),  x2 = *(const f4*)(xr + 8);
  f4 x3 = *(const f4*)(xr + 12), x4 = *(const f4*)(xr + 16), x5 = *(const f4*)(xr + 20);
#pragma unroll
  for (int cc = 0; cc < 4; ++cc) {
    const float* w = s_w + cc * 24;
    float acc = s_b[cc];
#pragma unroll
    for (int q = 0; q < 4; ++q) acc = fmaf(x0[q], w[q], acc);
#pragma unroll
    for (int q = 0; q < 4; ++q) acc = fmaf(x1[q], w[4 + q], acc);
#pragma unroll
    for (int q = 0; q < 4; ++q) acc = fmaf(x2[q], w[8 + q], acc);
#pragma unroll
    for (int q = 0; q < 4; ++q) acc = fmaf(x3[q], w[12 + q], acc);
#pragma unroll
    for (int q = 0; q < 4; ++q) acc = fmaf(x4[q], w[16 + q], acc);
#pragma unroll
    for (int q = 0; q < 4; ++q) acc = fmaf(x5[q], w[20 + q], acc);
    s_dt[lane][cc] = (acc > 20.f) ? acc : log1pf(__expf(acc));
  }
}

__global__ __launch_bounds__(256) void k_scanA(
    const float* __restrict__ xdbl, const float* __restrict__ xi,
    const float* __restrict__ A_log,
    const float* __restrict__ dtw, const float* __restrict__ dtbias,
    float* __restrict__ Hloc, float* __restrict__ Sdt) {
  __shared__ float s_dt[4][64][4], s_w[4][96], s_b[4][4];
  int b = blockIdx.y, seg = blockIdx.z;
  int tid = threadIdx.x, w = tid >> 6, lane = tid & 63;
  int ch0 = scan_ch0_w(blockIdx.x, w);
  int c = lane >> 4, n = lane & 15;
  int d = ch0 + c;
  for (int i = lane; i < 96; i += 64) s_w[w][i] = dtw[ch0 * 24 + i];
  if (lane < 4) s_b[w][lane] = dtbias[ch0 + lane];
  size_t rowbase = (size_t)b * 2048 + seg * 64;
  __syncthreads();
  dt_inline(xdbl, rowbase, lane, s_w[w], s_b[w], s_dt[w]);
  __syncthreads();
  float a = -__expf(A_log[d * 16 + n]);
  float h = 0.f, sdt = 0.f;
  size_t row = rowbase;
#pragma unroll 4
  for (int i = 0; i < 64; ++i, ++row) {
    float dtv = s_dt[w][i][c];
    float xiv = xi[row * 768 + d];
    float Bv = xdbl[row * 56 + 24 + n];
    float da = __expf(dtv * a);
    h = fmaf(da, h, dtv * Bv * xiv);
    sdt += dtv;
  }
  size_t o = (((size_t)b * 32 + seg) * 768 + d) * 16 + n;
  Hloc[o] = h;
  if (n == 0) Sdt[((size_t)b * 32 + seg) * 768 + d] = sdt;
}

__global__ __launch_bounds__(256) void k_scanC(
    const float* __restrict__ xdbl, const float* __restrict__ xi,
    const float* __restrict__ xz, const float* __restrict__ A_log,
    const float* __restrict__ Dp,
    const float* __restrict__ dtw, const float* __restrict__ dtbias,
    const float* __restrict__ Hloc, const float* __restrict__ Sdt,
    u16* __restrict__ y) {
  __shared__ float s_dt[4][64][4], s_y[4][64][4], s_w[4][96], s_b[4][4];
  int b = blockIdx.y, seg = blockIdx.z;
  int tid = threadIdx.x, w = tid >> 6, lane = tid & 63;
  int ch0 = scan_ch0_w(blockIdx.x, w);
  int c = lane >> 4, n = lane & 15;
  int d = ch0 + c;
  for (int i = lane; i < 96; i += 64) s_w[w][i] = dtw[ch0 * 24 + i];
  if (lane < 4) s_b[w][lane] = dtbias[ch0 + lane];
  size_t rowbase = (size_t)b * 2048 + seg * 64;
  __syncthreads();
  dt_inline(xdbl, rowbase, lane, s_w[w], s_b[w], s_dt[w]);
  float a = -__expf(A_log[d * 16 + n]);
  float h = 0.f;
  for (int s = 0; s < seg; ++s) {
    float P = __expf(a * Sdt[((size_t)b * 32 + s) * 768 + d]);
    h = fmaf(P, h, Hloc[(((size_t)b * 32 + s) * 768 + d) * 16 + n]);
  }
  __syncthreads();
  size_t row = rowbase;
#pragma unroll 2
  for (int i = 0; i < 64; ++i, ++row) {
    float dtv = s_dt[w][i][c];
    float xiv = xi[row * 768 + d];
    float Bv = xdbl[row * 56 + 24 + n];
    float Cv = xdbl[row * 56 + 40 + n];
    float da = __expf(dtv * a);
    h = fmaf(da, h, dtv * Bv * xiv);
    float yv = h * Cv;
    yv += __shfl_xor(yv, 1);
    yv += __shfl_xor(yv, 2);
    yv += __shfl_xor(yv, 4);
    yv += __shfl_xor(yv, 8);
    if (n == 0) s_y[w][i][c] = yv;
  }
  __syncthreads();
  size_t rw = rowbase + lane;
  f4 xiv4 = *(const f4*)(xi + rw * 768 + ch0);
  f4 dpv = *(const f4*)(Dp + ch0);
  f4 zv = *(const f4*)(xz + rw * 1536 + 768 + ch0);
  u16x4 ob;
#pragma unroll
  for (int e = 0; e < 4; ++e) {
    float o = (s_y[w][lane][e] + xiv4[e] * dpv[e]) * siluf(zv[e]);
    ob[e] = f2bf(o);
  }
  *(u16x4*)(y + rw * 768 + ch0) = ob;
}

// =====================================================================================
extern "C" void kernel_launch(void* const* d_in, const int* in_sizes, int n_in,
                              void* d_out, int out_size, void* d_ws, size_t ws_size,
                              hipStream_t stream) {
  const float* audio   = (const float*)d_in[0];
  const int*   tokens  = (const int*)d_in[1];
  const float* conv1_w = (const float*)d_in[2];
  const float* conv1_b = (const float*)d_in[3];
  const float* conv2_w = (const float*)d_in[4];
  const float* conv2_b = (const float*)d_in[5];
  const float* embedw  = (const float*)d_in[6];
  const float* P1[9], *P2[9];
  for (int i = 0; i < 9; ++i) { P1[i] = (const float*)d_in[7 + i]; P2[i] = (const float*)d_in[16 + i]; }
  const float* proj_w = (const float*)d_in[25];
  const float* proj_b = (const float*)d_in[26];
  (void)in_sizes; (void)n_in; (void)out_size; (void)ws_size;

  // ---- arena in d_out (fully overwritten by final GEMM) ----
  float* base = (float*)d_out;
  size_t off = 0;
  auto af = [&](size_t n) { float* p = base + off; off += n; return p; };
  float* xz   = af((size_t)4096 * 1536);
  float* xif  = af((size_t)4096 * 768);
  float* xdbl = af((size_t)4096 * 56);
  float* a1t  = af((size_t)2 * 1024 * 192);
  float* w1t  = af((size_t)80 * 3 * 192);
  float* w2t  = af((size_t)192 * 3 * 384);
  float* Hloc = af((size_t)2 * 32 * 768 * 16);
  float* Sdt  = af((size_t)2 * 32 * 768);
  u16* ub = (u16*)(base + off);
  size_t uoff = 0;
  auto au = [&](size_t n) { u16* p = ub + uoff; uoff += n; return p; };
  u16* Xin_b  = au((size_t)4096 * 384);
  u16* Xmid_b = au((size_t)4096 * 384);
  u16* xib    = au((size_t)4096 * 768);
  u16* yb16   = au((size_t)4096 * 768);
  u16* Wi1 = au((size_t)1536 * 384);
  u16* Wx1 = au((size_t)56 * 768);
  u16* Wo1 = au((size_t)384 * 768);
  u16* Wi2 = au((size_t)1536 * 384);
  u16* Wx2 = au((size_t)56 * 768);
  u16* Wo2 = au((size_t)384 * 768);
  u16* X2b    = (u16*)d_ws;                       // survive final GEMM's d_out writes
  u16* projwb = X2b + (size_t)4096 * 384;

  // ---- one batched weight-convert kernel (7 plain segments) ----
  CvtArgs ca;
  const float* srcs[7] = {P1[0], P1[3], P1[8], P2[0], P2[3], P2[8], proj_w};
  u16* dsts[7] = {Wi1, Wx1, Wo1, Wi2, Wx2, Wo2, projwb};
  int nqs[7] = {147456, 10752, 73728, 147456, 10752, 73728, 4824672};
  int cum = 0;
  for (int j = 0; j < 7; ++j) {
    ca.src[j] = srcs[j]; ca.dst[j] = dsts[j]; ca.nq[j] = nqs[j];
    ca.bstart[j] = cum; cum += (nqs[j] + 255) / 256;
  }
  ca.bstart[7] = cum;
  k_cvtmulti<<<dim3(cum), dim3(256), 0, stream>>>(ca);

  // ---- audio frontend + embedding -> Xin_b bf16 ----
  k_wtrans<<<dim3(180), dim3(256), 0, stream>>>(conv1_w, w1t, 192, 80);
  k_wtrans<<<dim3(864), dim3(256), 0, stream>>>(conv2_w, w2t, 384, 192);
  k_conv1<<<dim3(128), dim3(192), 0, stream>>>(audio, w1t, conv1_b, a1t);
  k_conv2b<<<dim3(256), dim3(384), 0, stream>>>(a1t, w2t, conv2_b, Xin_b);
  k_embedb<<<dim3(768), dim3(256), 0, stream>>>(tokens, embedw, Xin_b);

  auto run_mamba = [&](const float* const* P, const u16* Xin, u16* Xout,
                       const u16* Wi, const u16* Wx, const u16* Wo) {
    k_gemm2<64, 0, 0, 0, 1><<<dim3(64 * 24), dim3(256), 0, stream>>>(
        Xin, 384, Wi, 384, nullptr, xz, nullptr, 1536, 4096, 1536, 384);
    k_dwconv2<<<dim3(3072), dim3(256), 0, stream>>>(xz, P[1], P[2], xif, xib);
    k_gemm2<64, 0, 0, 0, 0><<<dim3(64 * 1), dim3(256), 0, stream>>>(
        xib, 768, Wx, 768, nullptr, xdbl, nullptr, 56, 4096, 56, 768);
    k_scanA<<<dim3(48, 2, 32), dim3(256), 0, stream>>>(
        xdbl, xif, P[6], P[4], P[5], Hloc, Sdt);
    k_scanC<<<dim3(48, 2, 32), dim3(256), 0, stream>>>(
        xdbl, xif, xz, P[6], P[7], P[4], P[5], Hloc, Sdt, yb16);
    k_gemm2<64, 0, 0, 1, 0><<<dim3(64 * 6), dim3(256), 0, stream>>>(
        yb16, 768, Wo, 768, nullptr, nullptr, Xout, 384, 4096, 384, 768);
  };
  run_mamba(P1, Xin_b, Xmid_b, Wi1, Wx1, Wo1);
  run_mamba(P2, Xmid_b, X2b, Wi2, Wx2, Wo2);

  // ---- final projection -> d_out [4096, 50257] f32 (v7: counted-vmcnt pipeline) ----
  k_gemmF<<<dim3(64 * 197), dim3(256), 0, stream>>>(
      X2b, projwb, proj_b, (float*)d_out, 50257, 50257);
}